// Round 9
// baseline (328.019 us; speedup 1.0000x reference)
//
#include <hip/hip_runtime.h>

// VQ-VAE vector quantizer, MI355X — v7: fused single-pass, quad-split D.
// Each token's 64 dims are split across 4 lanes (z[16]/lane) so register
// pressure is trivially low (the v3-v6 AGPR-parking pathology had the
// compiler shadowing z[64] out of arch VGPRs, inflating VALU ~2.5x).
// Dot partials combine via __shfl_xor(16)+__shfl_xor(32). Full codebook is
// processed in 4 x 32KB LDS chunks; epilogue (z_q_st, losses, hist) is fused
// (z still in regs), deleting the pairs round-trip (~144 us in v6).
// Inputs:  d_in[0] = z_e  f32 (32,64,64,64)  [B,D,H,W]
//          d_in[1] = emb  f32 (512,64)       [K,D]
// Output (flat f32): [0..8388608) z_q_st | [8388608..8388613) scalars
//                    (loss_vq, perplexity, codes_used, usage_ratio, avg_dist2)
//                    | [8388613..+131072) indices as float
// ws: [0..16) f64 sums | [16..2064) int counts[512] | [2064..4112) f32 see[512]

#define NTOK 131072
#define DDIM 64
#define KCB  512
#define HWSZ 4096
#define CHUNK 128          // codes per LDS chunk
#define NCHUNK 4
#define THREADS 1024       // 16 waves; 256 tokens/block

__global__ void vq_see_kernel(const float* __restrict__ emb,
                              float* __restrict__ see) {
  int k = blockIdx.x * 64 + threadIdx.x;
  if (k < KCB) {
    const float* e = emb + k * DDIM;
    float s = 0.f;
#pragma unroll
    for (int d = 0; d < DDIM; ++d) s = fmaf(e[d], e[d], s);
    see[k] = s;
  }
}

__global__ __launch_bounds__(THREADS, 4) void vq_fused_kernel(
    const float* __restrict__ z_e, const float* __restrict__ emb,
    const float* __restrict__ see, float* __restrict__ out,
    float* __restrict__ out_idx, int* __restrict__ counts,
    double* __restrict__ sums) {
  __shared__ float  ldsE[CHUNK * DDIM];   // 32 KB
  __shared__ float  ldsS[KCB];            // 2 KB
  __shared__ int    hist[KCB];            // 2 KB
  __shared__ double sq_s[16];
  __shared__ double md_s[16];

  const int tid   = threadIdx.x;
  const int tok16 = tid & 15;             // 16 consecutive tokens per wave
  const int dch   = (tid >> 4) & 3;       // which 16-dim chunk of the token
  const int wv    = tid >> 6;
  const int tok   = blockIdx.x * 256 + wv * 16 + tok16;
  const int b     = tok >> 12;
  const int hw    = tok & 4095;
  const int d0    = dch * 16;

  // init hist + stage see (visible after first chunk barrier)
  for (int i = tid; i < KCB; i += THREADS) { hist[i] = 0; ldsS[i] = see[i]; }

  // z: 16 dims per lane (lane-quad {tok16, dch} covers one token)
  const float* zp = z_e + (size_t)b * (DDIM * HWSZ) + (size_t)d0 * HWSZ + hw;
  float z[16];
#pragma unroll
  for (int j = 0; j < 16; ++j) z[j] = zp[(size_t)j * HWSZ];

  // ||z||^2: per-lane 16-dim partial, pairwise combine (deterministic)
  float pz = 0.f;
#pragma unroll
  for (int j = 0; j < 16; ++j) pz = fmaf(z[j], z[j], pz);
  float t1 = pz + __shfl_xor(pz, 16, 64);
  const float szz = t1 + __shfl_xor(t1, 32, 64);

  float best = 3.4e38f;
  int   bidx = 0;

  for (int ch = 0; ch < NCHUNK; ++ch) {
    __syncthreads();                      // protect LDS reuse
    {
      const float4* src =
          reinterpret_cast<const float4*>(emb + ch * (CHUNK * DDIM));
      float4* dst = reinterpret_cast<float4*>(ldsE);
#pragma unroll
      for (int v = tid; v < CHUNK * DDIM / 4; v += THREADS) dst[v] = src[v];
    }
    __syncthreads();

    const int kb = ch * CHUNK;
#pragma unroll 1
    for (int kk = 0; kk < CHUNK; kk += 8) {
      float a[8];
#pragma unroll
      for (int c = 0; c < 8; ++c) {
        const float4* ep =
            reinterpret_cast<const float4*>(ldsE + (kk + c) * DDIM + d0);
        float acc = 0.f;
#pragma unroll
        for (int j4 = 0; j4 < 4; ++j4) {
          const float4 e = ep[j4];        // 4 distinct addrs/wave, 2-way banks
          acc = fmaf(z[4 * j4 + 0], e.x, acc);
          acc = fmaf(z[4 * j4 + 1], e.y, acc);
          acc = fmaf(z[4 * j4 + 2], e.z, acc);
          acc = fmaf(z[4 * j4 + 3], e.w, acc);
        }
        a[c] = acc;
      }
#pragma unroll
      for (int c = 0; c < 8; ++c) {
        const float s1  = a[c] + __shfl_xor(a[c], 16, 64);
        const float dot = s1 + __shfl_xor(s1, 32, 64);
        const int   k   = kb + kk + c;
        // dist = (szz + see_k) - 2*dot  (fp32 op order as reference)
        const float dist = (szz + ldsS[k]) - 2.f * dot;
        if (dist < best) { best = dist; bidx = k; }   // strict <, ascending k
      }
    }
  }

  // ---- fused epilogue: z still in registers ----
  if (dch == 0) {
    atomicAdd(&hist[bidx], 1);
    out_idx[tok] = (float)bidx;
  }

  const float4* eq =
      reinterpret_cast<const float4*>(emb + bidx * DDIM + d0);  // L2-resident
  float* op = out + (size_t)b * (DDIM * HWSZ) + (size_t)d0 * HWSZ + hw;

  double sq = 0.0;
#pragma unroll
  for (int j4 = 0; j4 < 4; ++j4) {
    const float4 e = eq[j4];
    const float zq[4] = {e.x, e.y, e.z, e.w};
#pragma unroll
    for (int c2 = 0; c2 < 4; ++c2) {
      const int j = j4 * 4 + c2;
      const float df  = zq[c2] - z[j];     // fp32 round
      const float val = z[j] + df;         // z_e + (z_q - z_e), fp32 round
      op[(size_t)j * HWSZ] = val;
      sq = fma((double)df, (double)df, sq);
    }
  }

  double md = (dch == 0) ? (double)best : 0.0;
#pragma unroll
  for (int off = 32; off > 0; off >>= 1) {
    sq += __shfl_down(sq, off);
    md += __shfl_down(md, off);
  }
  if ((tid & 63) == 0) { sq_s[wv] = sq; md_s[wv] = md; }
  __syncthreads();                         // also orders hist atomics
  if (tid == 0) {
    double tsq = 0.0, tmd = 0.0;
#pragma unroll
    for (int w = 0; w < 16; ++w) { tsq += sq_s[w]; tmd += md_s[w]; }
    unsafeAtomicAdd(&sums[0], tsq);
    unsafeAtomicAdd(&sums[1], tmd);
  }
  for (int i = tid; i < KCB; i += THREADS) {
    const int h = hist[i];
    if (h) atomicAdd(&counts[i], h);
  }
}

__global__ void vq_final_kernel(const int* __restrict__ counts,
                                const double* __restrict__ sums,
                                float* __restrict__ scal) {
  __shared__ double ent_s[8];
  __shared__ int    used_s[8];
  const int tid = threadIdx.x;  // 512 threads
  const int c = counts[tid];
  const double p = (double)c / 131072.0;
  double e = (c > 0) ? (-p * log(p)) : 0.0;
  int u = (c > 0) ? 1 : 0;
#pragma unroll
  for (int off = 32; off > 0; off >>= 1) {
    e += __shfl_down(e, off);
    u += __shfl_down(u, off);
  }
  if ((tid & 63) == 0) { ent_s[tid >> 6] = e; used_s[tid >> 6] = u; }
  __syncthreads();
  if (tid == 0) {
    double ent = 0.0; int used = 0;
#pragma unroll
    for (int w = 0; w < 8; ++w) { ent += ent_s[w]; used += used_s[w]; }
    const double mse = sums[0] / 8388608.0;        // mean over B*D*H*W
    scal[0] = (float)(mse * 64.0 * 1.25);          // loss_vq = (1+beta)*mse*D
    scal[1] = (float)exp(ent);                     // perplexity
    scal[2] = (float)used;                         // codes_used
    scal[3] = (float)used / 512.f;                 // usage_ratio
    scal[4] = (float)(sums[1] / 131072.0);         // avg_dist2
  }
}

extern "C" void kernel_launch(void* const* d_in, const int* in_sizes, int n_in,
                              void* d_out, int out_size, void* d_ws,
                              size_t ws_size, hipStream_t stream) {
  const float* z_e = (const float*)d_in[0];
  const float* emb = (const float*)d_in[1];
  float* out = (float*)d_out;

  double* sums   = (double*)d_ws;
  int*    counts = (int*)((char*)d_ws + 16);
  float*  see    = (float*)((char*)d_ws + 2064);

  hipMemsetAsync(d_ws, 0, 2064, stream);
  vq_see_kernel<<<8, 64, 0, stream>>>(emb, see);
  vq_fused_kernel<<<NTOK / 256, THREADS, 0, stream>>>(
      z_e, emb, see, out, out + 8388613, counts, sums);
  vq_final_kernel<<<1, 512, 0, stream>>>(counts, sums, out + 8388608);
}

// Round 14
// 235.148 us; speedup vs baseline: 1.3949x; 1.3949x over previous
//
#include <hip/hip_runtime.h>

// VQ-VAE vector quantizer, MI355X — v8: register-tiled GEMM structure.
// Thread holds acc[4 tokens][8 codes] (32 regs); z streamed from LDS
// transposed [d][tok] (one per-lane float4/d), emb chunk streamed from LDS
// transposed [d][code] (two wave-uniform float4/d -> broadcast, cheap per
// v3/v5 evidence). Kills both measured pathologies: v3-v6 operand-register
// AGPR shadowing (no big per-thread operand arrays) and v7 DS-pipe
// saturation (3 LDS insts per 32 FMA insts; v7 was 6 DS per 16 FMA).
// Inputs:  d_in[0] = z_e  f32 (32,64,64,64)  [B,D,H,W]
//          d_in[1] = emb  f32 (512,64)       [K,D]
// Output (flat f32): [0..8388608) z_q_st | [8388608..8388613) scalars
//                    (loss_vq, perplexity, codes_used, usage_ratio, avg_dist2)
//                    | [8388613..+131072) indices as float
// ws: [0..16) f64 sums | [16..2064) int counts[512] | [2064..4112) f32 see[512]

#define NTOK 131072
#define DDIM 64
#define KCB 512
#define HWSZ 4096
#define TOKB 256      // tokens per block
#define CHUNK 128     // codes per LDS chunk
#define NCHUNK 4
#define THREADS 1024  // 16 waves
#define ETPITCH 132   // padded row pitch for ldsET

__global__ void vq_see_kernel(const float* __restrict__ emb,
                              float* __restrict__ see) {
  int k = blockIdx.x * 64 + threadIdx.x;
  if (k < KCB) {
    const float* e = emb + k * DDIM;
    float s = 0.f;
#pragma unroll
    for (int d = 0; d < DDIM; ++d) s = fmaf(e[d], e[d], s);
    see[k] = s;
  }
}

__global__ __launch_bounds__(THREADS) void vq_gemm_kernel(
    const float* __restrict__ z_e, const float* __restrict__ emb,
    const float* __restrict__ see, float* __restrict__ out,
    float* __restrict__ out_idx, int* __restrict__ counts,
    double* __restrict__ sums) {
  // manual layout (ldsET aliased as the reduction buffer after chunks end)
  __shared__ __attribute__((aligned(16))) char smem[105728];
  float*  ldsZ  = (float*)smem;                    // [64][256]  65536 B
  float*  ldsET = (float*)(smem + 65536);          // [64][132]  33792 B
  float2* ldsRed = (float2*)(smem + 65536);        // [16][258]  33024 B (alias)
  float*  ldsS  = (float*)(smem + 99328);          // [512]       2048 B
  float*  ldsSZ = (float*)(smem + 101376);         // [256]       1024 B
  float2* ldsFin = (float2*)(smem + 102400);       // [256]       2048 B
  int*    hist  = (int*)(smem + 104448);           // [256] (vestigial)
  double* sq_s  = (double*)(smem + 105472);        // [16]         128 B
  double* md_s  = (double*)(smem + 105600);        // [16]         128 B

  const int tid = threadIdx.x;
  const int tg  = tid & 63;                        // token-group (4 tokens)
  const int cg  = tid >> 6;                        // code-group == wave id
  const int tok0 = blockIdx.x * TOKB;
  const int b    = tok0 >> 12;
  const int hw0  = tok0 & 4095;
  const float* zbase = z_e + (size_t)b * (DDIM * HWSZ) + hw0;

  // ---- stage z transposed: ldsZ[d][t] = z_e[b][d][hw0+t] (coalesced) ----
#pragma unroll
  for (int r = 0; r < 4; ++r) {
    const int flat4 = r * 1024 + tid;              // float4 index in [0,4096)
    const int d = flat4 >> 6;
    const int rem = flat4 & 63;                    // float4 within d-row
    const float4 v =
        *reinterpret_cast<const float4*>(zbase + (size_t)d * HWSZ + rem * 4);
    *reinterpret_cast<float4*>(ldsZ + d * 256 + rem * 4) = v;
  }
  // stage see
  if (tid < KCB) ldsS[tid] = see[tid];
  __syncthreads();

  // ---- szz per token (sequential d, reference rounding) ----
  if (tid < TOKB) {
    float s = 0.f;
#pragma unroll
    for (int d = 0; d < DDIM; ++d) {
      const float zv = ldsZ[d * 256 + tid];
      s = fmaf(zv, zv, s);
    }
    ldsSZ[tid] = s;
  }
  __syncthreads();

  float szz_r[4];
#pragma unroll
  for (int i = 0; i < 4; ++i) szz_r[i] = ldsSZ[tg * 4 + i];

  float best[4] = {3.4e38f, 3.4e38f, 3.4e38f, 3.4e38f};
  int   bidx[4] = {0, 0, 0, 0};
  const int cg8 = cg * 8;

  for (int ch = 0; ch < NCHUNK; ++ch) {
    __syncthreads();
    // stage emb chunk transposed: ldsET[d][c'] = emb[ch*128+c'][d]
#pragma unroll
    for (int r = 0; r < 2; ++r) {
      const int flat4 = r * 1024 + tid;            // [0,2048)
      const int cc = flat4 >> 4;                   // code' 0..127
      const int d0 = (flat4 & 15) * 4;
      const float4 v = *reinterpret_cast<const float4*>(
          emb + (size_t)(ch * CHUNK + cc) * DDIM + d0);
      ldsET[(d0 + 0) * ETPITCH + cc] = v.x;
      ldsET[(d0 + 1) * ETPITCH + cc] = v.y;
      ldsET[(d0 + 2) * ETPITCH + cc] = v.z;
      ldsET[(d0 + 3) * ETPITCH + cc] = v.w;
    }
    __syncthreads();

    float acc[4][8];
#pragma unroll
    for (int i = 0; i < 4; ++i)
#pragma unroll
      for (int j = 0; j < 8; ++j) acc[i][j] = 0.f;

#pragma unroll 8
    for (int d = 0; d < DDIM; ++d) {
      const float4 zv = *reinterpret_cast<const float4*>(ldsZ + d * 256 + tg * 4);
      const float4 ea = *reinterpret_cast<const float4*>(ldsET + d * ETPITCH + cg8);
      const float4 eb = *reinterpret_cast<const float4*>(ldsET + d * ETPITCH + cg8 + 4);
      const float zz[4] = {zv.x, zv.y, zv.z, zv.w};
      const float ee[8] = {ea.x, ea.y, ea.z, ea.w, eb.x, eb.y, eb.z, eb.w};
#pragma unroll
      for (int i = 0; i < 4; ++i)
#pragma unroll
        for (int j = 0; j < 8; ++j)
          acc[i][j] = fmaf(zz[i], ee[j], acc[i][j]);
    }

    // dists + per-thread argmin (codes ascend within thread: ch outer, j inner)
#pragma unroll
    for (int j = 0; j < 8; ++j) {
      const int k = ch * CHUNK + cg8 + j;
      const float sek = ldsS[k];
#pragma unroll
      for (int i = 0; i < 4; ++i) {
        const float dist = (szz_r[i] + sek) - 2.f * acc[i][j];
        if (dist < best[i]) { best[i] = dist; bidx[i] = k; }
      }
    }
  }

  // ---- cross-wave (cg) argmin reduction ----
  __syncthreads();                                 // all done reading ldsET
#pragma unroll
  for (int i = 0; i < 4; ++i) {
    float2 p; p.x = best[i]; p.y = __int_as_float(bidx[i]);
    ldsRed[cg * 258 + tg * 4 + i] = p;
  }
  if (tid < 256) hist[tid] = 0;
  __syncthreads();

  double md = 0.0;
  if (tid < TOKB) {
    float fb = 3.4e38f; int fi = 0x7fffffff;
#pragma unroll
    for (int q = 0; q < 16; ++q) {
      const float2 p = ldsRed[q * 258 + tid];
      const int pi = __float_as_int(p.y);
      // lexicographic (dist, idx): == reference first-occurrence argmin
      if (p.x < fb || (p.x == fb && pi < fi)) { fb = p.x; fi = pi; }
    }
    float2 f; f.x = fb; f.y = __int_as_float(fi);
    ldsFin[tid] = f;
    out_idx[tok0 + tid] = (float)fi;
    md = (double)fb;
  }
  __syncthreads();

  // histogram: direct global atomics (131K adds over 512 counters ~ 1-2 us)
  if (tid < TOKB) {
    const int fi = __float_as_int(ldsFin[tid].y);
    atomicAdd(&counts[fi], 1);
  }

  // ---- fused epilogue: 16 (tok,d) elements per thread ----
  double sq = 0.0;
#pragma unroll
  for (int r = 0; r < 16; ++r) {
    const int flat = r * 1024 + tid;               // [0,16384)
    const int t = flat & 255;
    const int d = flat >> 8;
    const float ze = ldsZ[d * 256 + t];
    const int fi = __float_as_int(ldsFin[t].y);
    const float zq = emb[(size_t)fi * DDIM + d];   // L2-resident gather
    const float df = zq - ze;                      // fp32 round
    const float val = ze + df;                     // z_e + (z_q - z_e)
    out[(size_t)b * (DDIM * HWSZ) + (size_t)d * HWSZ + hw0 + t] = val;
    sq = fma((double)df, (double)df, sq);
  }

  // block-reduce sq, md (f64) -> one atomic pair
#pragma unroll
  for (int off = 32; off > 0; off >>= 1) {
    sq += __shfl_down(sq, off);
    md += __shfl_down(md, off);
  }
  if ((tid & 63) == 0) { sq_s[tid >> 6] = sq; md_s[tid >> 6] = md; }
  __syncthreads();
  if (tid == 0) {
    double tsq = 0.0, tmd = 0.0;
#pragma unroll
    for (int w = 0; w < 16; ++w) { tsq += sq_s[w]; tmd += md_s[w]; }
    unsafeAtomicAdd(&sums[0], tsq);
    unsafeAtomicAdd(&sums[1], tmd);
  }
}

__global__ void vq_final_kernel(const int* __restrict__ counts,
                                const double* __restrict__ sums,
                                float* __restrict__ scal) {
  __shared__ double ent_s[8];
  __shared__ int    used_s[8];
  const int tid = threadIdx.x;  // 512 threads
  const int c = counts[tid];
  const double p = (double)c / 131072.0;
  double e = (c > 0) ? (-p * log(p)) : 0.0;
  int u = (c > 0) ? 1 : 0;
#pragma unroll
  for (int off = 32; off > 0; off >>= 1) {
    e += __shfl_down(e, off);
    u += __shfl_down(u, off);
  }
  if ((tid & 63) == 0) { ent_s[tid >> 6] = e; used_s[tid >> 6] = u; }
  __syncthreads();
  if (tid == 0) {
    double ent = 0.0; int used = 0;
#pragma unroll
    for (int w = 0; w < 8; ++w) { ent += ent_s[w]; used += used_s[w]; }
    const double mse = sums[0] / 8388608.0;        // mean over B*D*H*W
    scal[0] = (float)(mse * 64.0 * 1.25);          // loss_vq = (1+beta)*mse*D
    scal[1] = (float)exp(ent);                     // perplexity
    scal[2] = (float)used;                         // codes_used
    scal[3] = (float)used / 512.f;                 // usage_ratio
    scal[4] = (float)(sums[1] / 131072.0);         // avg_dist2
  }
}

extern "C" void kernel_launch(void* const* d_in, const int* in_sizes, int n_in,
                              void* d_out, int out_size, void* d_ws,
                              size_t ws_size, hipStream_t stream) {
  const float* z_e = (const float*)d_in[0];
  const float* emb = (const float*)d_in[1];
  float* out = (float*)d_out;

  double* sums   = (double*)d_ws;
  int*    counts = (int*)((char*)d_ws + 16);
  float*  see    = (float*)((char*)d_ws + 2064);

  hipMemsetAsync(d_ws, 0, 2064, stream);
  vq_see_kernel<<<8, 64, 0, stream>>>(emb, see);
  vq_gemm_kernel<<<NTOK / TOKB, THREADS, 0, stream>>>(
      z_e, emb, see, out, out + 8388613, counts, sums);
  vq_final_kernel<<<1, 512, 0, stream>>>(counts, sums, out + 8388608);
}